// Round 11
// baseline (306.080 us; speedup 1.0000x reference)
//
#include <hip/hip_runtime.h>
#include <hip/hip_bf16.h>
#include <cstdint>

#define NHEAD 16
#define DHEAD 128
#define DMODEL 2048
#define TSEQ 2048
#define BATCH 2

using bf16 = __hip_bfloat16;
typedef __attribute__((ext_vector_type(4))) float  f32x4;
typedef __attribute__((ext_vector_type(2))) float  f32x2;
typedef __attribute__((ext_vector_type(4))) float  float4_t;
typedef __attribute__((ext_vector_type(4))) short  s16x4;
typedef __bf16 bf16x8 __attribute__((ext_vector_type(8)));

#define GLOAD_LDS16(gptr, lptr)                                                        \
  __builtin_amdgcn_global_load_lds((const __attribute__((address_space(1))) void*)(gptr), \
                                   (__attribute__((address_space(3))) void*)(lptr), 16, 0, 0)

#if __has_builtin(__builtin_amdgcn_exp2f)
#define EXP2(x) __builtin_amdgcn_exp2f(x)
#else
#define EXP2(x) exp2f(x)
#endif

__device__ __forceinline__ float bf2f(bf16 v) { return __bfloat162float(v); }
__device__ __forceinline__ bf16  f2bf(float f) { return __float2bfloat16(f); }
__device__ __forceinline__ unsigned short bfbits(float f) {
  return __builtin_bit_cast(unsigned short, f2bf(f));
}
__device__ __forceinline__ unsigned int pack2(float a, float b) {
  return (unsigned int)bfbits(a) | ((unsigned int)bfbits(b) << 16);
}

// ---------------------------------------------------------------- cast fp32 -> bf16
__global__ void cast_f32_to_bf16(const float* __restrict__ in, unsigned short* __restrict__ out, int n4) {
  int stride = gridDim.x * blockDim.x;
  for (int i = blockIdx.x * blockDim.x + threadIdx.x; i < n4; i += stride) {
    float4_t v = reinterpret_cast<const float4_t*>(in)[i];
    s16x4 r;
    r.x = (short)bfbits(v.x);
    r.y = (short)bfbits(v.y);
    r.z = (short)bfbits(v.z);
    r.w = (short)bfbits(v.w);
    reinterpret_cast<s16x4*>(out)[i] = r;
  }
}

// ---------------------------------------------------------------- RoPE tables (fp32 packed, [T][64] of (cos,sin))
__global__ void rope_tables(f32x2* __restrict__ cstab) {
  int i = blockIdx.x * blockDim.x + threadIdx.x;
  if (i >= TSEQ * 64) return;
  int t = i >> 6, f = i & 63;
  float inv = __expf(-((2.0f * (float)f) / 128.0f) * logf(10000.0f));
  float ang = (float)t * inv;
  f32x2 cs;
  cs.x = cosf(ang);
  cs.y = sinf(ang);
  cstab[i] = cs;
}

// ---------------------------------------------------------------- V -> V^T  ([B,H,D,T]) via LDS tiles
__global__ void transpose_v(const unsigned short* __restrict__ qkv, unsigned short* __restrict__ vt) {
  __shared__ short tile[64][132];
  const int bh = blockIdx.y;
  const int b = bh >> 4, h = bh & 15;
  const int t0 = blockIdx.x * 64;
  const int tid = threadIdx.x;
#pragma unroll
  for (int p = 0; p < 8; ++p) {
    int row  = p * 8 + (tid >> 5);
    int col  = (tid & 31) * 4;
    const unsigned short* src = qkv + (size_t)(b * TSEQ + t0 + row) * (3 * DMODEL) + 2 * DMODEL + h * DHEAD + col;
    s16x4 v = *reinterpret_cast<const s16x4*>(src);
    *reinterpret_cast<s16x4*>(&tile[row][col]) = v;
  }
  __syncthreads();
#pragma unroll
  for (int q = 0; q < 8; ++q) {
    int idx = q * 256 + tid;
    int d = idx >> 4, tq = idx & 15;
    s16x4 r;
    r.x = tile[tq * 4 + 0][d];
    r.y = tile[tq * 4 + 1][d];
    r.z = tile[tq * 4 + 2][d];
    r.w = tile[tq * 4 + 3][d];
    *reinterpret_cast<s16x4*>(vt + (size_t)(bh * DHEAD + d) * TSEQ + t0 + tq * 4) = r;
  }
}

// ---------------------------------------------------------------- C store helpers
__device__ __forceinline__ void store_c(float* p, float v) { *p = v; }
__device__ __forceinline__ void store_c(unsigned short* p, float v) { *p = bfbits(v); }

// ---------------------------------------------------------------- phase-interleaved 256x256 GEMM (qkv)
// r10 structure + T4 counted vmcnt: half-tile staging (A0@ph0, A1@ph1, B0@ph2,
// B1@ph3, 2 loads/thread each), boundary waits vmcnt(2) (B1' may stay in flight;
// never drains to 0 in-loop), ph0-mid vmcnt(2) forces B1 before ph1 needs it.
// Deadlines: ph0 reads A0,A1 (per-wave half) + B-half0; ph1 reads B-half1.
template <typename CT, bool ROPE>
__global__ __launch_bounds__(512, 2) void gemm_8p(const unsigned short* __restrict__ A,
                                                  const unsigned short* __restrict__ B,
                                                  CT* __restrict__ C, int M, int N, int K,
                                                  const f32x2* __restrict__ cstab) {
  __shared__ __align__(16) unsigned short As[2][256 * 64];   // 64 KB
  __shared__ __align__(16) unsigned short Bs[2][256 * 64];   // 64 KB

  const int tid  = threadIdx.x;
  const int lane = tid & 63;
  const int wave = tid >> 6;
  const int lrow = lane >> 4, lcol = lane & 15;
  const int wm2 = wave >> 2, wn4 = wave & 3;

  // bijective XCD swizzle (gridDim.x % 8 == 0)
  const int cpx = gridDim.x >> 3;
  const int bid = (blockIdx.x & 7) * cpx + (blockIdx.x >> 3);
  const int nby = N >> 8;
  const int m0 = (bid / nby) * 256;
  const int n0 = (bid % nby) * 256;
  const int NT = K >> 6;

  f32x4 acc[8][4] = {};   // [Mfrag 0..7][N slot 0..3], slot s -> nf = wn4 + 4s

  // stage HALF-tile h (rows h*128..h*128+127) of one matrix: 2 loads/thread.
  // LDS linear dest; global source chunk pre-swizzled (^= row&7).
#define STAGE_H(MAT, BASE, slot, h, k0)                                           \
  {                                                                               \
    _Pragma("unroll")                                                             \
    for (int it_ = 0; it_ < 2; ++it_) {                                           \
      int CC_ = it_ * 512 + tid;                                                  \
      int R_ = (h) * 128 + (CC_ >> 3), c_ = CC_ & 7;                              \
      GLOAD_LDS16(MAT + (size_t)((BASE) + R_) * K + (k0) + ((c_ ^ (R_ & 7)) << 3),\
                  (char*)(&slot[0]) + (h) * 16384 + CC_ * 16);                    \
    }                                                                             \
  }

  // fragment read: row R (lane m/n = lcol), k-chunk = ks*4 + lrow, swizzled by lcol&7
#define RD_FRAG(BASE, R, ks)                                                 \
  (*reinterpret_cast<const bf16x8*>(                                         \
      (BASE) + (R) * 128 + (((((ks) << 2) + lrow) ^ (lcol & 7)) << 4)))

#define WAITV2 asm volatile("s_waitcnt vmcnt(2)" ::: "memory")
#define WAITV0 asm volatile("s_waitcnt vmcnt(0)" ::: "memory")
#define BAR    { __builtin_amdgcn_s_barrier(); __builtin_amdgcn_sched_barrier(0); }

  // prologue: stage all 4 halves of tile 0, force A0,A1,B0 (allow B1 in flight)
  STAGE_H(A, m0, As[0], 0, 0);
  STAGE_H(A, m0, As[0], 1, 0);
  STAGE_H(B, n0, Bs[0], 0, 0);
  STAGE_H(B, n0, Bs[0], 1, 0);
  WAITV2;
  BAR;

  for (int t = 0; t < NT; ++t) {
    const char* Ab = (const char*)(&As[t & 1][0]);
    const char* Bb = (const char*)(&Bs[t & 1][0]);
    const bool pf = (t + 1 < NT);
    const int psl = (t + 1) & 1;
    const int pk0 = (t + 1) << 6;

    bf16x8 af[4][2], bfr[2][2];

    // ---- phase 0: quadrant (M0, N-slots 0,1); stage A-half0(t+1); force B1(t)
#pragma unroll
    for (int mf = 0; mf < 4; ++mf)
#pragma unroll
      for (int ks = 0; ks < 2; ++ks)
        af[mf][ks] = RD_FRAG(Ab, wm2 * 128 + mf * 16 + lcol, ks);
#pragma unroll
    for (int si = 0; si < 2; ++si)
#pragma unroll
      for (int ks = 0; ks < 2; ++ks)
        bfr[si][ks] = RD_FRAG(Bb, (wn4 + 4 * si) * 16 + lcol, ks);
    if (pf) { STAGE_H(A, m0, As[psl], 0, pk0); WAITV2; } else { WAITV0; }
    BAR;
    __builtin_amdgcn_s_setprio(1);
#pragma unroll
    for (int mf = 0; mf < 4; ++mf)
#pragma unroll
      for (int si = 0; si < 2; ++si)
#pragma unroll
        for (int ks = 0; ks < 2; ++ks)
          acc[mf][si] = __builtin_amdgcn_mfma_f32_16x16x32_bf16(af[mf][ks], bfr[si][ks], acc[mf][si], 0, 0, 0);
    __builtin_amdgcn_s_setprio(0);
    BAR;

    // ---- phase 1: quadrant (M0, N-slots 2,3); stage A-half1(t+1)
#pragma unroll
    for (int si = 0; si < 2; ++si)
#pragma unroll
      for (int ks = 0; ks < 2; ++ks)
        bfr[si][ks] = RD_FRAG(Bb, (wn4 + 4 * (2 + si)) * 16 + lcol, ks);
    if (pf) STAGE_H(A, m0, As[psl], 1, pk0);
    BAR;
    __builtin_amdgcn_s_setprio(1);
#pragma unroll
    for (int mf = 0; mf < 4; ++mf)
#pragma unroll
      for (int si = 0; si < 2; ++si)
#pragma unroll
        for (int ks = 0; ks < 2; ++ks)
          acc[mf][2 + si] = __builtin_amdgcn_mfma_f32_16x16x32_bf16(af[mf][ks], bfr[si][ks], acc[mf][2 + si], 0, 0, 0);
    __builtin_amdgcn_s_setprio(0);
    BAR;

    // ---- phase 2: quadrant (M1, N-slots 2,3); stage B-half0(t+1)
#pragma unroll
    for (int mf = 0; mf < 4; ++mf)
#pragma unroll
      for (int ks = 0; ks < 2; ++ks)
        af[mf][ks] = RD_FRAG(Ab, wm2 * 128 + (4 + mf) * 16 + lcol, ks);
    if (pf) STAGE_H(B, n0, Bs[psl], 0, pk0);
    BAR;
    __builtin_amdgcn_s_setprio(1);
#pragma unroll
    for (int mf = 0; mf < 4; ++mf)
#pragma unroll
      for (int si = 0; si < 2; ++si)
#pragma unroll
        for (int ks = 0; ks < 2; ++ks)
          acc[4 + mf][2 + si] = __builtin_amdgcn_mfma_f32_16x16x32_bf16(af[mf][ks], bfr[si][ks], acc[4 + mf][2 + si], 0, 0, 0);
    __builtin_amdgcn_s_setprio(0);
    BAR;

    // ---- phase 3: quadrant (M1, N-slots 0,1); stage B-half1(t+1)
#pragma unroll
    for (int si = 0; si < 2; ++si)
#pragma unroll
      for (int ks = 0; ks < 2; ++ks)
        bfr[si][ks] = RD_FRAG(Bb, (wn4 + 4 * si) * 16 + lcol, ks);
    if (pf) STAGE_H(B, n0, Bs[psl], 1, pk0);
    BAR;
    __builtin_amdgcn_s_setprio(1);
#pragma unroll
    for (int mf = 0; mf < 4; ++mf)
#pragma unroll
      for (int si = 0; si < 2; ++si)
#pragma unroll
        for (int ks = 0; ks < 2; ++ks)
          acc[4 + mf][si] = __builtin_amdgcn_mfma_f32_16x16x32_bf16(af[mf][ks], bfr[si][ks], acc[4 + mf][si], 0, 0, 0);
    __builtin_amdgcn_s_setprio(0);

    // ---- K-tile boundary: counted wait (A0',A1',B0' landed; B1' may fly)
    if (pf) { WAITV2; } 
    BAR;
  }
#undef STAGE_H
#undef RD_FRAG
#undef WAITV2
#undef WAITV0
#undef BAR

  // ---- epilogue ----
  if (ROPE && n0 < 2 * DMODEL) {
    const float qsc = (n0 < DMODEL) ? 0.12751743f : 1.0f;   // 1/sqrt(128) * log2e for q
    const int f = wn4 * 16 + lcol;
#pragma unroll
    for (int mi = 0; mi < 8; ++mi)
#pragma unroll
      for (int j = 0; j < 4; ++j) {
        const int r = m0 + wm2 * 128 + mi * 16 + lrow * 4 + j;
        const int t = r & (TSEQ - 1);
        const f32x2 cs = cstab[t * 64 + f];
        const float a1 = acc[mi][0][j], a2 = acc[mi][1][j];
        store_c(C + (size_t)r * N + n0 + f,       (a1 * cs.x - a2 * cs.y) * qsc);
        store_c(C + (size_t)r * N + n0 + f + 64,  (a2 * cs.x + a1 * cs.y) * qsc);
        const float b1 = acc[mi][2][j], b2 = acc[mi][3][j];
        store_c(C + (size_t)r * N + n0 + f + 128, (b1 * cs.x - b2 * cs.y) * qsc);
        store_c(C + (size_t)r * N + n0 + f + 192, (b2 * cs.x + b1 * cs.y) * qsc);
      }
  } else {
#pragma unroll
    for (int mi = 0; mi < 8; ++mi)
#pragma unroll
      for (int si = 0; si < 4; ++si)
#pragma unroll
        for (int j = 0; j < 4; ++j) {
          const int r = m0 + wm2 * 128 + mi * 16 + lrow * 4 + j;
          const int c = n0 + (wn4 + 4 * si) * 16 + lcol;
          store_c(C + (size_t)r * N + c, acc[mi][si][j]);
        }
  }
}

// ---------------------------------------------------------------- bf16 GEMM, C = A(MxK) * B(NxK)^T, m97 structure (op proj)
template <typename CT>
__global__ __launch_bounds__(256, 2) void gemm_bt(const unsigned short* __restrict__ A,
                                                  const unsigned short* __restrict__ B,
                                                  CT* __restrict__ C, int M, int N, int K) {
  __shared__ unsigned short As[128 * 32];
  __shared__ unsigned short Bs[128 * 32];
  const int tid  = threadIdx.x;
  const int wave = tid >> 6, lane = tid & 63;
  const int m0 = blockIdx.x * 128, n0 = blockIdx.y * 128;
  const int wm = wave * 32;
  const int lrow = lane >> 4, lcol = lane & 15;
  f32x4 acc[2][8] = {};

  for (int k0 = 0; k0 < K; k0 += 32) {
#pragma unroll
    for (int it = 0; it < 2; ++it) {
      int chunk = wave * 2 + it;
      int eoff  = chunk * 512 + lane * 8;
      int row   = eoff >> 5, col = eoff & 31;
      GLOAD_LDS16(A + (size_t)(m0 + row) * K + k0 + col, As + chunk * 512);
      GLOAD_LDS16(B + (size_t)(n0 + row) * K + k0 + col, Bs + chunk * 512);
    }
    __syncthreads();
    bf16x8 af[2], bfr[8];
#pragma unroll
    for (int mi = 0; mi < 2; ++mi)
      af[mi] = *reinterpret_cast<const bf16x8*>(&As[(wm + mi * 16 + lcol) * 32 + lrow * 8]);
#pragma unroll
    for (int ni = 0; ni < 8; ++ni)
      bfr[ni] = *reinterpret_cast<const bf16x8*>(&Bs[(ni * 16 + lcol) * 32 + lrow * 8]);
#pragma unroll
    for (int mi = 0; mi < 2; ++mi)
#pragma unroll
      for (int ni = 0; ni < 8; ++ni)
        acc[mi][ni] = __builtin_amdgcn_mfma_f32_16x16x32_bf16(af[mi], bfr[ni], acc[mi][ni], 0, 0, 0);
    __syncthreads();
  }
#pragma unroll
  for (int mi = 0; mi < 2; ++mi)
#pragma unroll
    for (int ni = 0; ni < 8; ++ni)
#pragma unroll
      for (int j = 0; j < 4; ++j) {
        int r = m0 + wm + mi * 16 + lrow * 4 + j;
        int c = n0 + ni * 16 + lcol;
        store_c(C + (size_t)r * N + c, acc[mi][ni][j]);
      }
}

// ---------------------------------------------------------------- flash attention (causal) — r9 verified
__global__ __launch_bounds__(512, 4) void flash_attn(const unsigned short* __restrict__ qkv,
                                                     const unsigned short* __restrict__ vt,
                                                     unsigned short* __restrict__ out) {
  __shared__ unsigned short kb[2][64 * 128];
  __shared__ unsigned short vb[2][128 * 64];
  __shared__ unsigned short plds[8][16 * 64];

  const int tid  = threadIdx.x;
  const int wave = tid >> 6, lane = tid & 63;
  const int lrow = lane >> 4, lcol = lane & 15;
  const int h = blockIdx.y, b = blockIdx.z;
  const int q0b = blockIdx.x * 128;
  const int q0w = q0b + wave * 16;
  const size_t qkbase = (size_t)b * TSEQ * (3 * DMODEL);
  const unsigned short* kptr = qkv + qkbase + DMODEL + h * DHEAD;
  const unsigned short* vptr = vt + (size_t)((b * NHEAD + h) * DHEAD) * TSEQ;

  bf16x8 qf[4];
#pragma unroll
  for (int kk = 0; kk < 4; ++kk)
    qf[kk] = *reinterpret_cast<const bf16x8*>(
        qkv + qkbase + (size_t)(q0w + lcol) * (3 * DMODEL) + h * DHEAD + kk * 32 + lrow * 8);

  f32x4 o[8] = {};
  float m = -1.0e30f, l = 0.f;

  const int nsteps = 2 * blockIdx.x + 2;

#define STAGE_KV(bi, kv0s)                                                              \
  {                                                                                     \
    _Pragma("unroll")                                                                   \
    for (int c = 0; c < 2; ++c) {                                                       \
      int cc = c * 512 + tid;                                                           \
      int krow = cc >> 4, kchk = (cc & 15) ^ (krow & 7);                                \
      GLOAD_LDS16(kptr + (size_t)((kv0s) + krow) * (3 * DMODEL) + kchk * 8,             \
                  &kb[bi][cc * 8]);                                                     \
      int vrow = cc >> 3, vchk = (cc & 7) ^ (vrow & 7);                                 \
      GLOAD_LDS16(vptr + (size_t)vrow * TSEQ + (kv0s) + vchk * 8,                       \
                  &vb[bi][cc * 8]);                                                     \
    }                                                                                   \
  }

  STAGE_KV(0, 0);
  __syncthreads();

  int cur = 0;
  for (int s = 0; s < nsteps; ++s) {
    const int kv0 = s * 64;
    if (s + 1 < nsteps) STAGE_KV(cur ^ 1, kv0 + 64);

    if (kv0 <= q0w + 15) {
      const unsigned short* kbc = kb[cur];
      const unsigned short* vbc = vb[cur];

      f32x4 sc[4] = {};
      __builtin_amdgcn_s_setprio(1);
#pragma unroll
      for (int n = 0; n < 4; ++n) {
        const int r = n * 16 + lcol;
#pragma unroll
        for (int kk = 0; kk < 4; ++kk) {
          bf16x8 kf = *reinterpret_cast<const bf16x8*>(
              &kbc[r * 128 + (((kk * 4 + lrow) ^ (lcol & 7)) << 3)]);
          sc[n] = __builtin_amdgcn_mfma_f32_16x16x32_bf16(kf, qf[kk], sc[n], 0, 0, 0);
        }
      }
      __builtin_amdgcn_s_setprio(0);

      const bool diag = (kv0 + 63 > q0w);
      const int qi = q0w + lcol;
      float sv[16];
#pragma unroll
      for (int n = 0; n < 4; ++n)
#pragma unroll
        for (int j = 0; j < 4; ++j) {
          float v = sc[n][j];
          if (diag && (kv0 + n * 16 + lrow * 4 + j) > qi) v = -1.0e30f;
          sv[n * 4 + j] = v;
        }
      float t8[8];
#pragma unroll
      for (int j = 0; j < 8; ++j) t8[j] = fmaxf(sv[j], sv[j + 8]);
#pragma unroll
      for (int j = 0; j < 4; ++j) t8[j] = fmaxf(t8[j], t8[j + 4]);
      float pm = fmaxf(fmaxf(t8[0], t8[1]), fmaxf(t8[2], t8[3]));
      pm = fmaxf(pm, __shfl_xor(pm, 16));
      pm = fmaxf(pm, __shfl_xor(pm, 32));

      if (__any(pm > m + 11.5f)) {
        const float mn  = fmaxf(m, pm);
        const float fsc = EXP2(m - mn);
        m = mn;
        l *= fsc;
#pragma unroll
        for (int c = 0; c < 8; ++c) o[c] *= fsc;
      }

#pragma unroll
      for (int i = 0; i < 16; ++i) sv[i] = EXP2(sv[i] - m);
      float a8[8];
#pragma unroll
      for (int j = 0; j < 8; ++j) a8[j] = sv[j] + sv[j + 8];
#pragma unroll
      for (int j = 0; j < 4; ++j) a8[j] += a8[j + 4];
      float rs = (a8[0] + a8[1]) + (a8[2] + a8[3]);
      rs += __shfl_xor(rs, 16);
      rs += __shfl_xor(rs, 32);
      l += rs;

      char* pw = reinterpret_cast<char*>(&plds[wave][0]);
#pragma unroll
      for (int n = 0; n < 4; ++n)
#pragma unroll
        for (int j = 0; j < 4; j += 2) {
          int boff = (lcol << 7) + ((((n << 1) + (lrow >> 1)) ^ (lcol & 7)) << 4) +
                     ((lrow & 1) << 3) + (j << 1);
          *reinterpret_cast<unsigned int*>(pw + boff) = pack2(sv[n * 4 + j], sv[n * 4 + j + 1]);
        }
      asm volatile("s_waitcnt lgkmcnt(0)" ::: "memory");

      bf16x8 pf0 = *reinterpret_cast<const bf16x8*>(
          pw + (lcol << 7) + ((lrow ^ (lcol & 7)) << 4));
      bf16x8 pf1 = *reinterpret_cast<const bf16x8*>(
          pw + (lcol << 7) + (((4 + lrow) ^ (lcol & 7)) << 4));

      __builtin_amdgcn_s_setprio(1);
#pragma unroll
      for (int c = 0; c < 8; ++c) {
        const int d = c * 16 + lcol;
        bf16x8 vf0 = *reinterpret_cast<const bf16x8*>(
            &vbc[d * 64 + ((lrow ^ (lcol & 7)) << 3)]);
        o[c] = __builtin_amdgcn_mfma_f32_16x16x32_bf16(vf0, pf0, o[c], 0, 0, 0);
        bf16x8 vf1 = *reinterpret_cast<const bf16x8*>(
            &vbc[d * 64 + (((4 + lrow) ^ (lcol & 7)) << 3)]);
        o[c] = __builtin_amdgcn_mfma_f32_16x16x32_bf16(vf1, pf1, o[c], 0, 0, 0);
      }
      __builtin_amdgcn_s_setprio(0);
    }

    __syncthreads();
    cur ^= 1;
  }

  const float rl = 1.0f / l;
  const int trow = q0w + lcol;
#pragma unroll
  for (int c = 0; c < 8; ++c) {
    s16x4 st;
#pragma unroll
    for (int j = 0; j < 4; ++j) st[j] = (short)bfbits(o[c][j] * rl);
    *reinterpret_cast<s16x4*>(
        out + (size_t)(b * TSEQ + trow) * DMODEL + h * DHEAD + c * 16 + lrow * 4) = st;
  }
#undef STAGE_KV
}

// ---------------------------------------------------------------- launcher
extern "C" void kernel_launch(void* const* d_in, const int* in_sizes, int n_in,
                              void* d_out, int out_size, void* d_ws, size_t ws_size,
                              hipStream_t stream) {
  const float* x     = (const float*)d_in[0];
  const float* w_qkv = (const float*)d_in[1];
  const float* w_op  = (const float*)d_in[2];
  float* out = (float*)d_out;

  const size_t SZ_XB  = (size_t)4096 * 2048 * 2;
  const size_t SZ_WQ  = (size_t)6144 * 2048 * 2;
  const size_t SZ_WO  = (size_t)2048 * 2048 * 2;
  const size_t SZ_QKV = (size_t)4096 * 6144 * 2;
  const size_t SZ_VT  = (size_t)32 * 128 * 2048 * 2;
  const size_t SZ_AO  = (size_t)4096 * 2048 * 2;
  const size_t SZ_TAB = (size_t)2048 * 64 * 8;
  const size_t NEEDED = SZ_XB + SZ_WQ + SZ_WO + SZ_QKV + SZ_VT + SZ_AO + SZ_TAB;
  if (ws_size < NEEDED) return;

  char* p = (char*)d_ws;
  unsigned short* xb   = (unsigned short*)p; p += SZ_XB;
  unsigned short* wqb  = (unsigned short*)p; p += SZ_WQ;
  unsigned short* wob  = (unsigned short*)p; p += SZ_WO;
  unsigned short* qkv  = (unsigned short*)p; p += SZ_QKV;
  unsigned short* vt   = (unsigned short*)p; p += SZ_VT;
  unsigned short* ao   = (unsigned short*)p; p += SZ_AO;
  f32x2* cstab = (f32x2*)p; p += SZ_TAB;

  cast_f32_to_bf16<<<dim3(2048), dim3(256), 0, stream>>>(x, xb, 4096 * 2048 / 4);
  cast_f32_to_bf16<<<dim3(2048), dim3(256), 0, stream>>>(w_qkv, wqb, 6144 * 2048 / 4);
  cast_f32_to_bf16<<<dim3(2048), dim3(256), 0, stream>>>(w_op, wob, 2048 * 2048 / 4);
  rope_tables<<<dim3(512), dim3(256), 0, stream>>>(cstab);

  // qkv = x @ w_qkv^T with fused RoPE (+ q scale * log2e): 16x24 256^2 tiles = 384 blocks
  gemm_8p<unsigned short, true><<<dim3(384), dim3(512), 0, stream>>>(
      xb, wqb, qkv, 4096, 6144, 2048, cstab);
  // v -> v^T
  transpose_v<<<dim3(32, 32), dim3(256), 0, stream>>>(qkv, vt);
  // causal flash attention (512 blocks, all-resident)
  flash_attn<<<dim3(16, 16, 2), dim3(512), 0, stream>>>(qkv, vt, ao);
  // out = attn_out @ w_op^T (m97 structure, 512 blocks = full occupancy at this shape)
  gemm_bt<float><<<dim3(32, 16), dim3(256), 0, stream>>>(ao, wob, out, 4096, 2048, 2048);
}

// Round 12
// 280.137 us; speedup vs baseline: 1.0926x; 1.0926x over previous
//
#include <hip/hip_runtime.h>
#include <hip/hip_bf16.h>
#include <cstdint>

#define NHEAD 16
#define DHEAD 128
#define DMODEL 2048
#define TSEQ 2048
#define BATCH 2

using bf16 = __hip_bfloat16;
typedef __attribute__((ext_vector_type(4))) float  f32x4;
typedef __attribute__((ext_vector_type(2))) float  f32x2;
typedef __attribute__((ext_vector_type(4))) float  float4_t;
typedef __attribute__((ext_vector_type(4))) short  s16x4;
typedef __bf16 bf16x8 __attribute__((ext_vector_type(8)));

#define GLOAD_LDS16(gptr, lptr)                                                        \
  __builtin_amdgcn_global_load_lds((const __attribute__((address_space(1))) void*)(gptr), \
                                   (__attribute__((address_space(3))) void*)(lptr), 16, 0, 0)

#if __has_builtin(__builtin_amdgcn_exp2f)
#define EXP2(x) __builtin_amdgcn_exp2f(x)
#else
#define EXP2(x) exp2f(x)
#endif

__device__ __forceinline__ float bf2f(bf16 v) { return __bfloat162float(v); }
__device__ __forceinline__ bf16  f2bf(float f) { return __float2bfloat16(f); }
__device__ __forceinline__ unsigned short bfbits(float f) {
  return __builtin_bit_cast(unsigned short, f2bf(f));
}
__device__ __forceinline__ unsigned int pack2(float a, float b) {
  return (unsigned int)bfbits(a) | ((unsigned int)bfbits(b) << 16);
}

// ---------------------------------------------------------------- fused cast fp32 -> bf16 (all three inputs)
#define N4_X  (4096 * 2048 / 4)
#define N4_WQ (6144 * 2048 / 4)
#define N4_WO (2048 * 2048 / 4)
__global__ void cast_all(const float* __restrict__ x, const float* __restrict__ wq,
                         const float* __restrict__ wo, unsigned short* __restrict__ xb,
                         unsigned short* __restrict__ wqb, unsigned short* __restrict__ wob) {
  const int total = N4_X + N4_WQ + N4_WO;
  int stride = gridDim.x * blockDim.x;
  for (int i = blockIdx.x * blockDim.x + threadIdx.x; i < total; i += stride) {
    const float* src;
    unsigned short* dst;
    int j;
    if (i < N4_X)            { src = x;  dst = xb;  j = i; }
    else if (i < N4_X + N4_WQ) { src = wq; dst = wqb; j = i - N4_X; }
    else                     { src = wo; dst = wob; j = i - N4_X - N4_WQ; }
    float4_t v = reinterpret_cast<const float4_t*>(src)[j];
    s16x4 r;
    r.x = (short)bfbits(v.x);
    r.y = (short)bfbits(v.y);
    r.z = (short)bfbits(v.z);
    r.w = (short)bfbits(v.w);
    reinterpret_cast<s16x4*>(dst)[j] = r;
  }
}

// ---------------------------------------------------------------- RoPE tables (fp32 packed, [T][64] of (cos,sin))
__global__ void rope_tables(f32x2* __restrict__ cstab) {
  int i = blockIdx.x * blockDim.x + threadIdx.x;
  if (i >= TSEQ * 64) return;
  int t = i >> 6, f = i & 63;
  float inv = __expf(-((2.0f * (float)f) / 128.0f) * logf(10000.0f));
  float ang = (float)t * inv;
  f32x2 cs;
  cs.x = cosf(ang);
  cs.y = sinf(ang);
  cstab[i] = cs;
}

// ---------------------------------------------------------------- V -> V^T  ([B,H,D,T]) via LDS tiles
__global__ void transpose_v(const unsigned short* __restrict__ qkv, unsigned short* __restrict__ vt) {
  __shared__ short tile[64][132];
  const int bh = blockIdx.y;
  const int b = bh >> 4, h = bh & 15;
  const int t0 = blockIdx.x * 64;
  const int tid = threadIdx.x;
#pragma unroll
  for (int p = 0; p < 8; ++p) {
    int row  = p * 8 + (tid >> 5);
    int col  = (tid & 31) * 4;
    const unsigned short* src = qkv + (size_t)(b * TSEQ + t0 + row) * (3 * DMODEL) + 2 * DMODEL + h * DHEAD + col;
    s16x4 v = *reinterpret_cast<const s16x4*>(src);
    *reinterpret_cast<s16x4*>(&tile[row][col]) = v;
  }
  __syncthreads();
#pragma unroll
  for (int q = 0; q < 8; ++q) {
    int idx = q * 256 + tid;
    int d = idx >> 4, tq = idx & 15;
    s16x4 r;
    r.x = tile[tq * 4 + 0][d];
    r.y = tile[tq * 4 + 1][d];
    r.z = tile[tq * 4 + 2][d];
    r.w = tile[tq * 4 + 3][d];
    *reinterpret_cast<s16x4*>(vt + (size_t)(bh * DHEAD + d) * TSEQ + t0 + tq * 4) = r;
  }
}

// ---------------------------------------------------------------- C store helpers
__device__ __forceinline__ void store_c(float* p, float v) { *p = v; }
__device__ __forceinline__ void store_c(unsigned short* p, float v) { *p = bfbits(v); }

// ---------------------------------------------------------------- bf16 GEMM, C = A(MxK) * B(NxK)^T, m97 structure (r9-verified)
// Waves M-split so RoPE pairs (d, d+64) = (ni, ni+4) live in the same lane.
// ROPE=true: rotary on q,k thirds; q pre-scaled by (1/sqrt(DH))*log2(e).
template <typename CT, bool ROPE>
__global__ __launch_bounds__(256, 2) void gemm_bt(const unsigned short* __restrict__ A,
                                                  const unsigned short* __restrict__ B,
                                                  CT* __restrict__ C, int M, int N, int K,
                                                  const f32x2* __restrict__ cstab) {
  __shared__ unsigned short As[128 * 32];
  __shared__ unsigned short Bs[128 * 32];
  const int tid  = threadIdx.x;
  const int wave = tid >> 6, lane = tid & 63;
  const int m0 = blockIdx.x * 128, n0 = blockIdx.y * 128;
  const int wm = wave * 32;
  const int lrow = lane >> 4, lcol = lane & 15;
  f32x4 acc[2][8] = {};

  for (int k0 = 0; k0 < K; k0 += 32) {
#pragma unroll
    for (int it = 0; it < 2; ++it) {
      int chunk = wave * 2 + it;
      int eoff  = chunk * 512 + lane * 8;
      int row   = eoff >> 5, col = eoff & 31;
      GLOAD_LDS16(A + (size_t)(m0 + row) * K + k0 + col, As + chunk * 512);
      GLOAD_LDS16(B + (size_t)(n0 + row) * K + k0 + col, Bs + chunk * 512);
    }
    __syncthreads();
    bf16x8 af[2], bfr[8];
#pragma unroll
    for (int mi = 0; mi < 2; ++mi)
      af[mi] = *reinterpret_cast<const bf16x8*>(&As[(wm + mi * 16 + lcol) * 32 + lrow * 8]);
#pragma unroll
    for (int ni = 0; ni < 8; ++ni)
      bfr[ni] = *reinterpret_cast<const bf16x8*>(&Bs[(ni * 16 + lcol) * 32 + lrow * 8]);
#pragma unroll
    for (int mi = 0; mi < 2; ++mi)
#pragma unroll
      for (int ni = 0; ni < 8; ++ni)
        acc[mi][ni] = __builtin_amdgcn_mfma_f32_16x16x32_bf16(af[mi], bfr[ni], acc[mi][ni], 0, 0, 0);
    __syncthreads();
  }

  if (ROPE && n0 < 2 * DMODEL) {
    const float qsc = (n0 < DMODEL) ? 0.12751743f : 1.0f;   // 1/sqrt(128) * log2e for q
#pragma unroll
    for (int mi = 0; mi < 2; ++mi)
#pragma unroll
      for (int j = 0; j < 4; ++j) {
        const int r = m0 + wm + mi * 16 + lrow * 4 + j;
        const int t = r & (TSEQ - 1);
#pragma unroll
        for (int ni = 0; ni < 4; ++ni) {
          const int f = ni * 16 + lcol;
          const f32x2 cs = cstab[t * 64 + f];
          const float a1 = acc[mi][ni][j];
          const float a2 = acc[mi][ni + 4][j];
          store_c(C + (size_t)r * N + n0 + f,      (a1 * cs.x - a2 * cs.y) * qsc);
          store_c(C + (size_t)r * N + n0 + f + 64, (a2 * cs.x + a1 * cs.y) * qsc);
        }
      }
  } else {
#pragma unroll
    for (int mi = 0; mi < 2; ++mi)
#pragma unroll
      for (int ni = 0; ni < 8; ++ni)
#pragma unroll
        for (int j = 0; j < 4; ++j) {
          int r = m0 + wm + mi * 16 + lrow * 4 + j;
          int c = n0 + ni * 16 + lcol;
          store_c(C + (size_t)r * N + c, acc[mi][ni][j]);
        }
  }
}

// ---------------------------------------------------------------- flash attention (causal) — r9 verified
// + causal load-balance: co-resident blocks g and g+256 (same raw x, b=0/1 —
// MI355X XCD round-robin pairs them on one CU) get COMPLEMENTARY q-tiles via
// x = b ? 15-raw : raw, so every CU's pair sums to a constant 34 KV-steps.
__global__ __launch_bounds__(512, 4) void flash_attn(const unsigned short* __restrict__ qkv,
                                                     const unsigned short* __restrict__ vt,
                                                     unsigned short* __restrict__ out) {
  __shared__ unsigned short kb[2][64 * 128];
  __shared__ unsigned short vb[2][128 * 64];
  __shared__ unsigned short plds[8][16 * 64];

  const int tid  = threadIdx.x;
  const int wave = tid >> 6, lane = tid & 63;
  const int lrow = lane >> 4, lcol = lane & 15;
  const int h = blockIdx.y, b = blockIdx.z;
  const int x = b ? (15 - (int)blockIdx.x) : (int)blockIdx.x;   // complementary pairing
  const int q0b = x * 128;
  const int q0w = q0b + wave * 16;
  const size_t qkbase = (size_t)b * TSEQ * (3 * DMODEL);
  const unsigned short* kptr = qkv + qkbase + DMODEL + h * DHEAD;
  const unsigned short* vptr = vt + (size_t)((b * NHEAD + h) * DHEAD) * TSEQ;

  bf16x8 qf[4];
#pragma unroll
  for (int kk = 0; kk < 4; ++kk)
    qf[kk] = *reinterpret_cast<const bf16x8*>(
        qkv + qkbase + (size_t)(q0w + lcol) * (3 * DMODEL) + h * DHEAD + kk * 32 + lrow * 8);

  f32x4 o[8] = {};
  float m = -1.0e30f, l = 0.f;

  const int nsteps = 2 * x + 2;

#define STAGE_KV(bi, kv0s)                                                              \
  {                                                                                     \
    _Pragma("unroll")                                                                   \
    for (int c = 0; c < 2; ++c) {                                                       \
      int cc = c * 512 + tid;                                                           \
      int krow = cc >> 4, kchk = (cc & 15) ^ (krow & 7);                                \
      GLOAD_LDS16(kptr + (size_t)((kv0s) + krow) * (3 * DMODEL) + kchk * 8,             \
                  &kb[bi][cc * 8]);                                                     \
      int vrow = cc >> 3, vchk = (cc & 7) ^ (vrow & 7);                                 \
      GLOAD_LDS16(vptr + (size_t)vrow * TSEQ + (kv0s) + vchk * 8,                       \
                  &vb[bi][cc * 8]);                                                     \
    }                                                                                   \
  }

  STAGE_KV(0, 0);
  __syncthreads();

  int cur = 0;
  for (int s = 0; s < nsteps; ++s) {
    const int kv0 = s * 64;
    if (s + 1 < nsteps) STAGE_KV(cur ^ 1, kv0 + 64);

    if (kv0 <= q0w + 15) {
      const unsigned short* kbc = kb[cur];
      const unsigned short* vbc = vb[cur];

      f32x4 sc[4] = {};
      __builtin_amdgcn_s_setprio(1);
#pragma unroll
      for (int n = 0; n < 4; ++n) {
        const int r = n * 16 + lcol;
#pragma unroll
        for (int kk = 0; kk < 4; ++kk) {
          bf16x8 kf = *reinterpret_cast<const bf16x8*>(
              &kbc[r * 128 + (((kk * 4 + lrow) ^ (lcol & 7)) << 3)]);
          sc[n] = __builtin_amdgcn_mfma_f32_16x16x32_bf16(kf, qf[kk], sc[n], 0, 0, 0);
        }
      }
      __builtin_amdgcn_s_setprio(0);

      const bool diag = (kv0 + 63 > q0w);
      const int qi = q0w + lcol;
      float sv[16];
#pragma unroll
      for (int n = 0; n < 4; ++n)
#pragma unroll
        for (int j = 0; j < 4; ++j) {
          float v = sc[n][j];
          if (diag && (kv0 + n * 16 + lrow * 4 + j) > qi) v = -1.0e30f;
          sv[n * 4 + j] = v;
        }
      float t8[8];
#pragma unroll
      for (int j = 0; j < 8; ++j) t8[j] = fmaxf(sv[j], sv[j + 8]);
#pragma unroll
      for (int j = 0; j < 4; ++j) t8[j] = fmaxf(t8[j], t8[j + 4]);
      float pm = fmaxf(fmaxf(t8[0], t8[1]), fmaxf(t8[2], t8[3]));
      pm = fmaxf(pm, __shfl_xor(pm, 16));
      pm = fmaxf(pm, __shfl_xor(pm, 32));

      if (__any(pm > m + 11.5f)) {   // defer-max (T13, THR = 8 nats = 11.5 log2)
        const float mn  = fmaxf(m, pm);
        const float fsc = EXP2(m - mn);
        m = mn;
        l *= fsc;
#pragma unroll
        for (int c = 0; c < 8; ++c) o[c] *= fsc;
      }

#pragma unroll
      for (int i = 0; i < 16; ++i) sv[i] = EXP2(sv[i] - m);
      float a8[8];
#pragma unroll
      for (int j = 0; j < 8; ++j) a8[j] = sv[j] + sv[j + 8];
#pragma unroll
      for (int j = 0; j < 4; ++j) a8[j] += a8[j + 4];
      float rs = (a8[0] + a8[1]) + (a8[2] + a8[3]);
      rs += __shfl_xor(rs, 16);
      rs += __shfl_xor(rs, 32);
      l += rs;

      char* pw = reinterpret_cast<char*>(&plds[wave][0]);
#pragma unroll
      for (int n = 0; n < 4; ++n)
#pragma unroll
        for (int j = 0; j < 4; j += 2) {
          int boff = (lcol << 7) + ((((n << 1) + (lrow >> 1)) ^ (lcol & 7)) << 4) +
                     ((lrow & 1) << 3) + (j << 1);
          *reinterpret_cast<unsigned int*>(pw + boff) = pack2(sv[n * 4 + j], sv[n * 4 + j + 1]);
        }
      asm volatile("s_waitcnt lgkmcnt(0)" ::: "memory");

      bf16x8 pf0 = *reinterpret_cast<const bf16x8*>(
          pw + (lcol << 7) + ((lrow ^ (lcol & 7)) << 4));
      bf16x8 pf1 = *reinterpret_cast<const bf16x8*>(
          pw + (lcol << 7) + (((4 + lrow) ^ (lcol & 7)) << 4));

      __builtin_amdgcn_s_setprio(1);
#pragma unroll
      for (int c = 0; c < 8; ++c) {
        const int d = c * 16 + lcol;
        bf16x8 vf0 = *reinterpret_cast<const bf16x8*>(
            &vbc[d * 64 + ((lrow ^ (lcol & 7)) << 3)]);
        o[c] = __builtin_amdgcn_mfma_f32_16x16x32_bf16(vf0, pf0, o[c], 0, 0, 0);
        bf16x8 vf1 = *reinterpret_cast<const bf16x8*>(
            &vbc[d * 64 + (((4 + lrow) ^ (lcol & 7)) << 3)]);
        o[c] = __builtin_amdgcn_mfma_f32_16x16x32_bf16(vf1, pf1, o[c], 0, 0, 0);
      }
      __builtin_amdgcn_s_setprio(0);
    }

    __syncthreads();
    cur ^= 1;
  }

  const float rl = 1.0f / l;
  const int trow = q0w + lcol;
#pragma unroll
  for (int c = 0; c < 8; ++c) {
    s16x4 st;
#pragma unroll
    for (int j = 0; j < 4; ++j) st[j] = (short)bfbits(o[c][j] * rl);
    *reinterpret_cast<s16x4*>(
        out + (size_t)(b * TSEQ + trow) * DMODEL + h * DHEAD + c * 16 + lrow * 4) = st;
  }
#undef STAGE_KV
}

// ---------------------------------------------------------------- launcher
extern "C" void kernel_launch(void* const* d_in, const int* in_sizes, int n_in,
                              void* d_out, int out_size, void* d_ws, size_t ws_size,
                              hipStream_t stream) {
  const float* x     = (const float*)d_in[0];
  const float* w_qkv = (const float*)d_in[1];
  const float* w_op  = (const float*)d_in[2];
  float* out = (float*)d_out;

  const size_t SZ_XB  = (size_t)4096 * 2048 * 2;
  const size_t SZ_WQ  = (size_t)6144 * 2048 * 2;
  const size_t SZ_WO  = (size_t)2048 * 2048 * 2;
  const size_t SZ_QKV = (size_t)4096 * 6144 * 2;
  const size_t SZ_VT  = (size_t)32 * 128 * 2048 * 2;
  const size_t SZ_AO  = (size_t)4096 * 2048 * 2;
  const size_t SZ_TAB = (size_t)2048 * 64 * 8;
  const size_t NEEDED = SZ_XB + SZ_WQ + SZ_WO + SZ_QKV + SZ_VT + SZ_AO + SZ_TAB;
  if (ws_size < NEEDED) return;

  char* p = (char*)d_ws;
  unsigned short* xb   = (unsigned short*)p; p += SZ_XB;
  unsigned short* wqb  = (unsigned short*)p; p += SZ_WQ;
  unsigned short* wob  = (unsigned short*)p; p += SZ_WO;
  unsigned short* qkv  = (unsigned short*)p; p += SZ_QKV;
  unsigned short* vt   = (unsigned short*)p; p += SZ_VT;
  unsigned short* ao   = (unsigned short*)p; p += SZ_AO;
  f32x2* cstab = (f32x2*)p; p += SZ_TAB;

  cast_all<<<dim3(2048), dim3(256), 0, stream>>>(x, w_qkv, w_op, xb, wqb, wob);
  rope_tables<<<dim3(512), dim3(256), 0, stream>>>(cstab);

  // qkv = x @ w_qkv^T with fused RoPE (+ q scale * log2e) on the q,k thirds
  gemm_bt<unsigned short, true><<<dim3(32, 48), dim3(256), 0, stream>>>(
      xb, wqb, qkv, 4096, 6144, 2048, cstab);
  // v -> v^T
  transpose_v<<<dim3(32, 32), dim3(256), 0, stream>>>(qkv, vt);
  // causal flash attention (512 blocks, all-resident, CU-pair balanced)
  flash_attn<<<dim3(16, 16, 2), dim3(512), 0, stream>>>(qkv, vt, ao);
  // out = attn_out @ w_op^T
  gemm_bt<float, false><<<dim3(32, 16), dim3(256), 0, stream>>>(
      ao, wob, out, 4096, 2048, 2048, nullptr);
}

// Round 13
// 249.721 us; speedup vs baseline: 1.2257x; 1.1218x over previous
//
#include <hip/hip_runtime.h>
#include <hip/hip_bf16.h>
#include <cstdint>

#define NHEAD 16
#define DHEAD 128
#define DMODEL 2048
#define TSEQ 2048
#define BATCH 2

using bf16 = __hip_bfloat16;
typedef __attribute__((ext_vector_type(4))) float  f32x4;
typedef __attribute__((ext_vector_type(2))) float  f32x2;
typedef __attribute__((ext_vector_type(4))) float  float4_t;
typedef __attribute__((ext_vector_type(4))) short  s16x4;
typedef __bf16 bf16x8 __attribute__((ext_vector_type(8)));

#define GLOAD_LDS16(gptr, lptr)                                                        \
  __builtin_amdgcn_global_load_lds((const __attribute__((address_space(1))) void*)(gptr), \
                                   (__attribute__((address_space(3))) void*)(lptr), 16, 0, 0)

#if __has_builtin(__builtin_amdgcn_exp2f)
#define EXP2(x) __builtin_amdgcn_exp2f(x)
#else
#define EXP2(x) exp2f(x)
#endif

__device__ __forceinline__ float bf2f(bf16 v) { return __bfloat162float(v); }
__device__ __forceinline__ bf16  f2bf(float f) { return __float2bfloat16(f); }
__device__ __forceinline__ unsigned short bfbits(float f) {
  return __builtin_bit_cast(unsigned short, f2bf(f));
}
__device__ __forceinline__ unsigned int pack2(float a, float b) {
  return (unsigned int)bfbits(a) | ((unsigned int)bfbits(b) << 16);
}

// ---------------------------------------------------------------- fused cast fp32 -> bf16 (all three inputs)
#define N4_X  (4096 * 2048 / 4)
#define N4_WQ (6144 * 2048 / 4)
#define N4_WO (2048 * 2048 / 4)
__global__ void cast_all(const float* __restrict__ x, const float* __restrict__ wq,
                         const float* __restrict__ wo, unsigned short* __restrict__ xb,
                         unsigned short* __restrict__ wqb, unsigned short* __restrict__ wob) {
  const int total = N4_X + N4_WQ + N4_WO;
  int stride = gridDim.x * blockDim.x;
  for (int i = blockIdx.x * blockDim.x + threadIdx.x; i < total; i += stride) {
    const float* src;
    unsigned short* dst;
    int j;
    if (i < N4_X)            { src = x;  dst = xb;  j = i; }
    else if (i < N4_X + N4_WQ) { src = wq; dst = wqb; j = i - N4_X; }
    else                     { src = wo; dst = wob; j = i - N4_X - N4_WQ; }
    float4_t v = reinterpret_cast<const float4_t*>(src)[j];
    s16x4 r;
    r.x = (short)bfbits(v.x);
    r.y = (short)bfbits(v.y);
    r.z = (short)bfbits(v.z);
    r.w = (short)bfbits(v.w);
    reinterpret_cast<s16x4*>(dst)[j] = r;
  }
}

// ---------------------------------------------------------------- RoPE tables (fp32 packed, [T][64] of (cos,sin))
__global__ void rope_tables(f32x2* __restrict__ cstab) {
  int i = blockIdx.x * blockDim.x + threadIdx.x;
  if (i >= TSEQ * 64) return;
  int t = i >> 6, f = i & 63;
  float inv = __expf(-((2.0f * (float)f) / 128.0f) * logf(10000.0f));
  float ang = (float)t * inv;
  f32x2 cs;
  cs.x = cosf(ang);
  cs.y = sinf(ang);
  cstab[i] = cs;
}

// ---------------------------------------------------------------- C store helpers
__device__ __forceinline__ void store_c(float* p, float v) { *p = v; }
__device__ __forceinline__ void store_c(unsigned short* p, float v) { *p = bfbits(v); }

// ---------------------------------------------------------------- bf16 GEMM, C = A(MxK) * B(NxK)^T
// m97 scheduling (single-buffer global_load_lds + 2 barriers per K-tile) with
// BK=64: halves barrier count vs BK=32. 128-B LDS rows with the r10-verified
// 8-chunk XOR swizzle (linear LDS dest + pre-swizzled global source; ds_read
// applies the same involution) -> 2-way max bank conflict.
// Waves M-split so RoPE pairs (d, d+64) = (ni, ni+4) live in the same lane.
// ROPE: rotary on q,k thirds (q pre-scaled by (1/sqrt(DH))*log2e).
// VT: v third (n0 >= 2*DMODEL) is stored TRANSPOSED into vt[(b*16+h)*128+d][t]
//     (replaces the separate transpose_v kernel; qkv v-third store skipped).
template <typename CT, bool ROPE, bool VT>
__global__ __launch_bounds__(256, 2) void gemm_bt(const unsigned short* __restrict__ A,
                                                  const unsigned short* __restrict__ B,
                                                  CT* __restrict__ C, int M, int N, int K,
                                                  const f32x2* __restrict__ cstab,
                                                  unsigned short* __restrict__ vt) {
  __shared__ __align__(16) unsigned short As[128 * 64];   // 16 KB
  __shared__ __align__(16) unsigned short Bs[128 * 64];   // 16 KB
  const int tid  = threadIdx.x;
  const int wave = tid >> 6, lane = tid & 63;
  const int m0 = blockIdx.x * 128, n0 = blockIdx.y * 128;
  const int wm = wave * 32;
  const int lrow = lane >> 4, lcol = lane & 15;
  f32x4 acc[2][8] = {};

  // fragment read: row R, k-half ks: chunk = (ks*4 + lrow) ^ (R & 7)
#define RD_FRAG(BASE, R, ks)                                                    \
  (*reinterpret_cast<const bf16x8*>(                                            \
      (const char*)(BASE) + (R) * 128 + (((((ks) << 2) + lrow) ^ ((R) & 7)) << 4)))

  for (int k0 = 0; k0 < K; k0 += 64) {
    // stage 128x64 of A and B: 1024 chunks each, 4/thread; linear dest, swizzled src
#pragma unroll
    for (int it = 0; it < 4; ++it) {
      int CC = it * 256 + tid;
      int R = CC >> 3, ch = CC & 7;
      int kg = (ch ^ (R & 7)) << 3;
      GLOAD_LDS16(A + (size_t)(m0 + R) * K + k0 + kg, (char*)As + CC * 16);
      GLOAD_LDS16(B + (size_t)(n0 + R) * K + k0 + kg, (char*)Bs + CC * 16);
    }
    __syncthreads();
#pragma unroll
    for (int ks = 0; ks < 2; ++ks) {
      bf16x8 af[2], bfr[8];
#pragma unroll
      for (int mi = 0; mi < 2; ++mi)
        af[mi] = RD_FRAG(As, wm + mi * 16 + lcol, ks);
#pragma unroll
      for (int ni = 0; ni < 8; ++ni)
        bfr[ni] = RD_FRAG(Bs, ni * 16 + lcol, ks);
#pragma unroll
      for (int mi = 0; mi < 2; ++mi)
#pragma unroll
        for (int ni = 0; ni < 8; ++ni)
          acc[mi][ni] = __builtin_amdgcn_mfma_f32_16x16x32_bf16(af[mi], bfr[ni], acc[mi][ni], 0, 0, 0);
    }
    __syncthreads();
  }
#undef RD_FRAG

  if (ROPE && n0 < 2 * DMODEL) {
    const float qsc = (n0 < DMODEL) ? 0.12751743f : 1.0f;   // 1/sqrt(128) * log2e for q
#pragma unroll
    for (int mi = 0; mi < 2; ++mi)
#pragma unroll
      for (int j = 0; j < 4; ++j) {
        const int r = m0 + wm + mi * 16 + lrow * 4 + j;
        const int t = r & (TSEQ - 1);
#pragma unroll
        for (int ni = 0; ni < 4; ++ni) {
          const int f = ni * 16 + lcol;
          const f32x2 cs = cstab[t * 64 + f];
          const float a1 = acc[mi][ni][j];
          const float a2 = acc[mi][ni + 4][j];
          store_c(C + (size_t)r * N + n0 + f,      (a1 * cs.x - a2 * cs.y) * qsc);
          store_c(C + (size_t)r * N + n0 + f + 64, (a2 * cs.x + a1 * cs.y) * qsc);
        }
      }
  } else if (VT) {
    // v third: store transposed into vt[(b*16+h)*128 + d][t] (skip qkv store —
    // nothing reads the v third of qkv). Lane packs 4 consecutive t (j=0..3).
    const int h = (n0 - 2 * DMODEL) >> 7;
#pragma unroll
    for (int mi = 0; mi < 2; ++mi) {
      const int r0 = m0 + wm + mi * 16 + lrow * 4;
      const int b = r0 >> 11, t0 = r0 & (TSEQ - 1);
#pragma unroll
      for (int ni = 0; ni < 8; ++ni) {
        const int d = ni * 16 + lcol;
        s16x4 v4;
#pragma unroll
        for (int j = 0; j < 4; ++j) v4[j] = (short)bfbits(acc[mi][ni][j]);
        *reinterpret_cast<s16x4*>(
            vt + (size_t)((b * NHEAD + h) * DHEAD + d) * TSEQ + t0) = v4;
      }
    }
  } else {
#pragma unroll
    for (int mi = 0; mi < 2; ++mi)
#pragma unroll
      for (int ni = 0; ni < 8; ++ni)
#pragma unroll
        for (int j = 0; j < 4; ++j) {
          int r = m0 + wm + mi * 16 + lrow * 4 + j;
          int c = n0 + ni * 16 + lcol;
          store_c(C + (size_t)r * N + c, acc[mi][ni][j]);
        }
  }
}

// ---------------------------------------------------------------- flash attention (causal) — r12 verified
// 8 waves x 16 q-rows; KV staged once per block, double-buffered, XOR-swizzled.
// Complementary CU-pair balance: x = b ? 15-raw : raw.
__global__ __launch_bounds__(512, 4) void flash_attn(const unsigned short* __restrict__ qkv,
                                                     const unsigned short* __restrict__ vt,
                                                     unsigned short* __restrict__ out) {
  __shared__ unsigned short kb[2][64 * 128];
  __shared__ unsigned short vb[2][128 * 64];
  __shared__ unsigned short plds[8][16 * 64];

  const int tid  = threadIdx.x;
  const int wave = tid >> 6, lane = tid & 63;
  const int lrow = lane >> 4, lcol = lane & 15;
  const int h = blockIdx.y, b = blockIdx.z;
  const int x = b ? (15 - (int)blockIdx.x) : (int)blockIdx.x;
  const int q0b = x * 128;
  const int q0w = q0b + wave * 16;
  const size_t qkbase = (size_t)b * TSEQ * (3 * DMODEL);
  const unsigned short* kptr = qkv + qkbase + DMODEL + h * DHEAD;
  const unsigned short* vptr = vt + (size_t)((b * NHEAD + h) * DHEAD) * TSEQ;

  bf16x8 qf[4];
#pragma unroll
  for (int kk = 0; kk < 4; ++kk)
    qf[kk] = *reinterpret_cast<const bf16x8*>(
        qkv + qkbase + (size_t)(q0w + lcol) * (3 * DMODEL) + h * DHEAD + kk * 32 + lrow * 8);

  f32x4 o[8] = {};
  float m = -1.0e30f, l = 0.f;

  const int nsteps = 2 * x + 2;

#define STAGE_KV(bi, kv0s)                                                              \
  {                                                                                     \
    _Pragma("unroll")                                                                   \
    for (int c = 0; c < 2; ++c) {                                                       \
      int cc = c * 512 + tid;                                                           \
      int krow = cc >> 4, kchk = (cc & 15) ^ (krow & 7);                                \
      GLOAD_LDS16(kptr + (size_t)((kv0s) + krow) * (3 * DMODEL) + kchk * 8,             \
                  &kb[bi][cc * 8]);                                                     \
      int vrow = cc >> 3, vchk = (cc & 7) ^ (vrow & 7);                                 \
      GLOAD_LDS16(vptr + (size_t)vrow * TSEQ + (kv0s) + vchk * 8,                       \
                  &vb[bi][cc * 8]);                                                     \
    }                                                                                   \
  }

  STAGE_KV(0, 0);
  __syncthreads();

  int cur = 0;
  for (int s = 0; s < nsteps; ++s) {
    const int kv0 = s * 64;
    if (s + 1 < nsteps) STAGE_KV(cur ^ 1, kv0 + 64);

    if (kv0 <= q0w + 15) {
      const unsigned short* kbc = kb[cur];
      const unsigned short* vbc = vb[cur];

      f32x4 sc[4] = {};
      __builtin_amdgcn_s_setprio(1);
#pragma unroll
      for (int n = 0; n < 4; ++n) {
        const int r = n * 16 + lcol;
#pragma unroll
        for (int kk = 0; kk < 4; ++kk) {
          bf16x8 kf = *reinterpret_cast<const bf16x8*>(
              &kbc[r * 128 + (((kk * 4 + lrow) ^ (lcol & 7)) << 3)]);
          sc[n] = __builtin_amdgcn_mfma_f32_16x16x32_bf16(kf, qf[kk], sc[n], 0, 0, 0);
        }
      }
      __builtin_amdgcn_s_setprio(0);

      const bool diag = (kv0 + 63 > q0w);
      const int qi = q0w + lcol;
      float sv[16];
#pragma unroll
      for (int n = 0; n < 4; ++n)
#pragma unroll
        for (int j = 0; j < 4; ++j) {
          float v = sc[n][j];
          if (diag && (kv0 + n * 16 + lrow * 4 + j) > qi) v = -1.0e30f;
          sv[n * 4 + j] = v;
        }
      float t8[8];
#pragma unroll
      for (int j = 0; j < 8; ++j) t8[j] = fmaxf(sv[j], sv[j + 8]);
#pragma unroll
      for (int j = 0; j < 4; ++j) t8[j] = fmaxf(t8[j], t8[j + 4]);
      float pm = fmaxf(fmaxf(t8[0], t8[1]), fmaxf(t8[2], t8[3]));
      pm = fmaxf(pm, __shfl_xor(pm, 16));
      pm = fmaxf(pm, __shfl_xor(pm, 32));

      if (__any(pm > m + 11.5f)) {   // defer-max (T13, THR = 8 nats = 11.5 log2)
        const float mn  = fmaxf(m, pm);
        const float fsc = EXP2(m - mn);
        m = mn;
        l *= fsc;
#pragma unroll
        for (int c = 0; c < 8; ++c) o[c] *= fsc;
      }

#pragma unroll
      for (int i = 0; i < 16; ++i) sv[i] = EXP2(sv[i] - m);
      float a8[8];
#pragma unroll
      for (int j = 0; j < 8; ++j) a8[j] = sv[j] + sv[j + 8];
#pragma unroll
      for (int j = 0; j < 4; ++j) a8[j] += a8[j + 4];
      float rs = (a8[0] + a8[1]) + (a8[2] + a8[3]);
      rs += __shfl_xor(rs, 16);
      rs += __shfl_xor(rs, 32);
      l += rs;

      char* pw = reinterpret_cast<char*>(&plds[wave][0]);
#pragma unroll
      for (int n = 0; n < 4; ++n)
#pragma unroll
        for (int j = 0; j < 4; j += 2) {
          int boff = (lcol << 7) + ((((n << 1) + (lrow >> 1)) ^ (lcol & 7)) << 4) +
                     ((lrow & 1) << 3) + (j << 1);
          *reinterpret_cast<unsigned int*>(pw + boff) = pack2(sv[n * 4 + j], sv[n * 4 + j + 1]);
        }
      asm volatile("s_waitcnt lgkmcnt(0)" ::: "memory");

      bf16x8 pf0 = *reinterpret_cast<const bf16x8*>(
          pw + (lcol << 7) + ((lrow ^ (lcol & 7)) << 4));
      bf16x8 pf1 = *reinterpret_cast<const bf16x8*>(
          pw + (lcol << 7) + (((4 + lrow) ^ (lcol & 7)) << 4));

      __builtin_amdgcn_s_setprio(1);
#pragma unroll
      for (int c = 0; c < 8; ++c) {
        const int d = c * 16 + lcol;
        bf16x8 vf0 = *reinterpret_cast<const bf16x8*>(
            &vbc[d * 64 + ((lrow ^ (lcol & 7)) << 3)]);
        o[c] = __builtin_amdgcn_mfma_f32_16x16x32_bf16(vf0, pf0, o[c], 0, 0, 0);
        bf16x8 vf1 = *reinterpret_cast<const bf16x8*>(
            &vbc[d * 64 + (((4 + lrow) ^ (lcol & 7)) << 3)]);
        o[c] = __builtin_amdgcn_mfma_f32_16x16x32_bf16(vf1, pf1, o[c], 0, 0, 0);
      }
      __builtin_amdgcn_s_setprio(0);
    }

    __syncthreads();
    cur ^= 1;
  }

  const float rl = 1.0f / l;
  const int trow = q0w + lcol;
#pragma unroll
  for (int c = 0; c < 8; ++c) {
    s16x4 st;
#pragma unroll
    for (int j = 0; j < 4; ++j) st[j] = (short)bfbits(o[c][j] * rl);
    *reinterpret_cast<s16x4*>(
        out + (size_t)(b * TSEQ + trow) * DMODEL + h * DHEAD + c * 16 + lrow * 4) = st;
  }
#undef STAGE_KV
}

// ---------------------------------------------------------------- launcher
extern "C" void kernel_launch(void* const* d_in, const int* in_sizes, int n_in,
                              void* d_out, int out_size, void* d_ws, size_t ws_size,
                              hipStream_t stream) {
  const float* x     = (const float*)d_in[0];
  const float* w_qkv = (const float*)d_in[1];
  const float* w_op  = (const float*)d_in[2];
  float* out = (float*)d_out;

  const size_t SZ_XB  = (size_t)4096 * 2048 * 2;
  const size_t SZ_WQ  = (size_t)6144 * 2048 * 2;
  const size_t SZ_WO  = (size_t)2048 * 2048 * 2;
  const size_t SZ_QKV = (size_t)4096 * 6144 * 2;
  const size_t SZ_VT  = (size_t)32 * 128 * 2048 * 2;
  const size_t SZ_AO  = (size_t)4096 * 2048 * 2;
  const size_t SZ_TAB = (size_t)2048 * 64 * 8;
  const size_t NEEDED = SZ_XB + SZ_WQ + SZ_WO + SZ_QKV + SZ_VT + SZ_AO + SZ_TAB;
  if (ws_size < NEEDED) return;

  char* p = (char*)d_ws;
  unsigned short* xb   = (unsigned short*)p; p += SZ_XB;
  unsigned short* wqb  = (unsigned short*)p; p += SZ_WQ;
  unsigned short* wob  = (unsigned short*)p; p += SZ_WO;
  unsigned short* qkv  = (unsigned short*)p; p += SZ_QKV;
  unsigned short* vt   = (unsigned short*)p; p += SZ_VT;
  unsigned short* ao   = (unsigned short*)p; p += SZ_AO;
  f32x2* cstab = (f32x2*)p; p += SZ_TAB;

  cast_all<<<dim3(2048), dim3(256), 0, stream>>>(x, w_qkv, w_op, xb, wqb, wob);
  rope_tables<<<dim3(512), dim3(256), 0, stream>>>(cstab);

  // qkv = x @ w_qkv^T with fused RoPE (+ q scale * log2e) on q,k thirds and
  // fused transposed V store (v third -> vt directly)
  gemm_bt<unsigned short, true, true><<<dim3(32, 48), dim3(256), 0, stream>>>(
      xb, wqb, qkv, 4096, 6144, 2048, cstab, vt);
  // causal flash attention (512 blocks, all-resident, CU-pair balanced)
  flash_attn<<<dim3(16, 16, 2), dim3(512), 0, stream>>>(qkv, vt, ao);
  // out = attn_out @ w_op^T
  gemm_bt<float, false, false><<<dim3(32, 16), dim3(256), 0, stream>>>(
      ao, wob, out, 4096, 2048, 2048, nullptr, nullptr);
}